// Round 4
// baseline (707.871 us; speedup 1.0000x reference)
//
#include <hip/hip_runtime.h>
#include <hip/hip_bf16.h>

#define N_NODES 50000
#define N_EDGES 1600000
#define DIM 128
#define N_LAYERS 3
#define N_GRAPHS 128

#define NSLICE 8
#define SLICE_N (N_NODES / NSLICE)   // 6250 exactly
#define HCHUNK 16                     // hist: blocks per slice
#define FCHUNK 32                     // fill: blocks per slice

// ------------------------------------------------------------ bf16 helpers
__device__ __forceinline__ float bfu2f(unsigned short u) {
    union { unsigned int i; float f; } c; c.i = ((unsigned int)u) << 16; return c.f;
}
__device__ __forceinline__ unsigned short f2bfu(float f) {
    __hip_bfloat16 h = __float2bfloat16(f);  // RNE
    return *reinterpret_cast<unsigned short*>(&h);
}

// ---------------------------------------------------------------- utilities
__global__ void zero2_kernel(int* __restrict__ a, int* __restrict__ b, int n) {
    int i = blockIdx.x * blockDim.x + threadIdx.x;
    if (i < n) { a[i] = 0; b[i] = 0; }
}

// x (f32) -> xb (bf16), vectorized
__global__ __launch_bounds__(256) void cvt_kernel(const float4* __restrict__ x,
                                                  ushort4* __restrict__ xb, int n4) {
    int i = blockIdx.x * blockDim.x + threadIdx.x;
    if (i < n4) {
        float4 v = x[i];
        ushort4 o;
        o.x = f2bfu(v.x); o.y = f2bfu(v.y); o.z = f2bfu(v.z); o.w = f2bfu(v.w);
        xb[i] = o;
    }
}

// ------------------------------------------------------------- CSR building
// XCD-sliced histogram: slice = blockIdx&7 so (round-robin dispatch) each XCD
// owns one 6250-node slice; LDS histogram cuts global atomics ~4x and confines
// them to the slice's L2.
__global__ __launch_bounds__(256) void hist_slice_kernel(const int* __restrict__ ei,
                                                         int* __restrict__ deg) {
    __shared__ int h[SLICE_N];
    const int slice = blockIdx.x & 7;
    const int chunk = blockIdx.x >> 3;
    const int lo = slice * SLICE_N, hi = lo + SLICE_N;
    for (int i = threadIdx.x; i < SLICE_N; i += 256) h[i] = 0;
    __syncthreads();
    const int per = (N_EDGES + HCHUNK - 1) / HCHUNK;
    const int e0 = chunk * per;
    const int e1 = min(e0 + per, N_EDGES);
    for (int e = e0 + threadIdx.x; e < e1; e += 256) {
        int d = ei[N_EDGES + e];
        if (d >= lo && d < hi) atomicAdd(&h[d - lo], 1);
    }
    __syncthreads();
    for (int i = threadIdx.x; i < SLICE_N; i += 256) {
        int v = h[i];
        if (v) atomicAdd(&deg[lo + i], v);
    }
}

// 3-phase parallel exclusive scan
__global__ __launch_bounds__(256) void scan_block_sums(const int* __restrict__ deg,
                                                       int* __restrict__ bsums, int n) {
    __shared__ int sd[256];
    int tid = threadIdx.x;
    int i = blockIdx.x * 256 + tid;
    sd[tid] = (i < n) ? deg[i] : 0;
    __syncthreads();
    for (int off = 1; off < 256; off <<= 1) {
        int t = (tid >= off) ? sd[tid - off] : 0;
        __syncthreads();
        sd[tid] += t;
        __syncthreads();
    }
    if (tid == 255) bsums[blockIdx.x] = sd[255];
}

__global__ __launch_bounds__(256) void scan_offsets(int* __restrict__ bsums, int nb) {
    __shared__ int sd[256];
    int tid = threadIdx.x;
    int v = (tid < nb) ? bsums[tid] : 0;
    sd[tid] = v;
    __syncthreads();
    for (int off = 1; off < 256; off <<= 1) {
        int t = (tid >= off) ? sd[tid - off] : 0;
        __syncthreads();
        sd[tid] += t;
        __syncthreads();
    }
    if (tid < nb) bsums[tid] = sd[tid] - v;  // exclusive
}

__global__ __launch_bounds__(256) void scan_write(const int* __restrict__ deg,
                                                  const int* __restrict__ bsums,
                                                  int* __restrict__ row_ptr,
                                                  float* __restrict__ inv_deg, int n) {
    __shared__ int sd[256];
    int tid = threadIdx.x;
    int i = blockIdx.x * 256 + tid;
    int v = (i < n) ? deg[i] : 0;
    sd[tid] = v;
    __syncthreads();
    for (int off = 1; off < 256; off <<= 1) {
        int t = (tid >= off) ? sd[tid - off] : 0;
        __syncthreads();
        sd[tid] += t;
        __syncthreads();
    }
    if (i < n) {
        row_ptr[i + 1] = bsums[blockIdx.x] + sd[tid];
        inv_deg[i] = (v > 0) ? 1.0f / (float)v : 0.0f;
    }
    if (i == 0) row_ptr[0] = 0;
}

// XCD-sliced CSR fill: atomics on fill[] and scattered csr writes confined to
// the slice's ~800KB region -> stays in one XCD's L2, writeback ~6.4MB total.
__global__ __launch_bounds__(256) void fill_slice_kernel(const int* __restrict__ ei,
                                                         const int* __restrict__ row_ptr,
                                                         int* __restrict__ fill,
                                                         int* __restrict__ csr) {
    const int slice = blockIdx.x & 7;
    const int chunk = blockIdx.x >> 3;
    const int lo = slice * SLICE_N, hi = lo + SLICE_N;
    const int per = (N_EDGES + FCHUNK - 1) / FCHUNK;
    const int e0 = chunk * per;
    const int e1 = min(e0 + per, N_EDGES);
    for (int e = e0 + threadIdx.x; e < e1; e += 256) {
        int d = ei[N_EDGES + e];
        if (d >= lo && d < hi) {
            int s = ei[e];
            int pos = atomicAdd(&fill[d], 1);
            csr[row_ptr[d] + pos] = s;
        }
    }
}

// ------------------------------------------------------------- aggregation
// one wave per node; lanes 0-31 handle even edge of a pair, 32-63 the odd one;
// each lane loads ushort4 (8B) = 4 features; unroll x2 (4 edges in flight);
// halves combined with shfl_xor(32) at the end.
__global__ __launch_bounds__(256) void agg_kernel(const ushort4* __restrict__ xb4,
                                                  const int* __restrict__ csr,
                                                  const int* __restrict__ row_ptr,
                                                  const float* __restrict__ inv_deg,
                                                  ushort4* __restrict__ aggb4, int n) {
    int gw = (blockIdx.x * blockDim.x + threadIdx.x) >> 6;
    int lane = threadIdx.x & 63;
    if (gw >= n) return;
    const int half = lane >> 5;
    const int sub  = lane & 31;
    int e0 = row_ptr[gw], e1 = row_ptr[gw + 1];
    float a0 = 0.f, a1 = 0.f, a2 = 0.f, a3 = 0.f;
    int e = e0;
    for (; e + 4 <= e1; e += 4) {
        int sA = csr[e + half];
        int sB = csr[e + 2 + half];
        ushort4 vA = xb4[(size_t)sA * 32 + sub];
        ushort4 vB = xb4[(size_t)sB * 32 + sub];
        a0 += bfu2f(vA.x) + bfu2f(vB.x);
        a1 += bfu2f(vA.y) + bfu2f(vB.y);
        a2 += bfu2f(vA.z) + bfu2f(vB.z);
        a3 += bfu2f(vA.w) + bfu2f(vB.w);
    }
    if (e + 2 <= e1) {
        int s = csr[e + half];
        ushort4 v = xb4[(size_t)s * 32 + sub];
        a0 += bfu2f(v.x); a1 += bfu2f(v.y); a2 += bfu2f(v.z); a3 += bfu2f(v.w);
        e += 2;
    }
    if (e < e1 && half == 0) {  // odd tail edge: low half only
        int s = csr[e];
        ushort4 v = xb4[(size_t)s * 32 + sub];
        a0 += bfu2f(v.x); a1 += bfu2f(v.y); a2 += bfu2f(v.z); a3 += bfu2f(v.w);
    }
    a0 += __shfl_xor(a0, 32);
    a1 += __shfl_xor(a1, 32);
    a2 += __shfl_xor(a2, 32);
    a3 += __shfl_xor(a3, 32);
    if (half == 0) {
        float w = inv_deg[gw];
        ushort4 o;
        o.x = f2bfu(a0 * w); o.y = f2bfu(a1 * w);
        o.z = f2bfu(a2 * w); o.w = f2bfu(a3 * w);
        aggb4[(size_t)gw * 32 + sub] = o;
    }
}

// ------------------------------------------------------------------- GEMM
// out = aggb @ Wl + xb @ Wr + bias (+ReLU). bf16 in; bf16 or f32 out.
#define GR 32
template <int OUT_BF16, int RELU>
__global__ __launch_bounds__(256) void gemm_kernel(const unsigned short* __restrict__ aggb,
                                                   const unsigned short* __restrict__ xb,
                                                   const float* __restrict__ Wl,
                                                   const float* __restrict__ Wr,
                                                   const float* __restrict__ bias,
                                                   unsigned short* __restrict__ outb,
                                                   float* __restrict__ outf, int n) {
    __shared__ float sA[GR][DIM];
    __shared__ float sX[GR][DIM];
    const int tid = threadIdx.x;
    const int row0 = blockIdx.x * GR;

    for (int idx = tid; idx < GR * 32; idx += 256) {
        int r = idx >> 5;
        int c4 = idx & 31;
        int gr = row0 + r;
        float4 va = make_float4(0.f, 0.f, 0.f, 0.f);
        float4 vx = va;
        if (gr < n) {
            ushort4 ua = ((const ushort4*)aggb)[(size_t)gr * 32 + c4];
            ushort4 ux = ((const ushort4*)xb)[(size_t)gr * 32 + c4];
            va = make_float4(bfu2f(ua.x), bfu2f(ua.y), bfu2f(ua.z), bfu2f(ua.w));
            vx = make_float4(bfu2f(ux.x), bfu2f(ux.y), bfu2f(ux.z), bfu2f(ux.w));
        }
        ((float4*)&sA[r][0])[c4] = va;
        ((float4*)&sX[r][0])[c4] = vx;
    }
    __syncthreads();

    const int jg = tid & 31;
    const int rg = tid >> 5;

    float acc[4][4];
#pragma unroll
    for (int m = 0; m < 4; m++)
#pragma unroll
        for (int c = 0; c < 4; c++) acc[m][c] = bias[jg + 32 * c];

    for (int k = 0; k < DIM; k += 4) {
        float wl[4][4], wr[4][4];
#pragma unroll
        for (int kk = 0; kk < 4; kk++)
#pragma unroll
            for (int c = 0; c < 4; c++) {
                wl[kk][c] = Wl[(k + kk) * DIM + jg + 32 * c];
                wr[kk][c] = Wr[(k + kk) * DIM + jg + 32 * c];
            }
#pragma unroll
        for (int m = 0; m < 4; m++) {
            int r = rg + 8 * m;
            float4 a  = *(const float4*)&sA[r][k];
            float4 xv = *(const float4*)&sX[r][k];
#pragma unroll
            for (int c = 0; c < 4; c++) {
                acc[m][c] += a.x * wl[0][c] + a.y * wl[1][c] + a.z * wl[2][c] + a.w * wl[3][c]
                           + xv.x * wr[0][c] + xv.y * wr[1][c] + xv.z * wr[2][c] + xv.w * wr[3][c];
            }
        }
    }

#pragma unroll
    for (int m = 0; m < 4; m++) {
        int gr = row0 + rg + 8 * m;
        if (gr < n) {
#pragma unroll
            for (int c = 0; c < 4; c++) {
                float v = acc[m][c];
                if (RELU) v = fmaxf(v, 0.f);
                if (OUT_BF16) outb[(size_t)gr * DIM + jg + 32 * c] = f2bfu(v);
                else          outf[(size_t)gr * DIM + jg + 32 * c] = v;
            }
        }
    }
}

// ------------------------------------------------------------------- pool
__global__ __launch_bounds__(1024) void pool_kernel(const float* __restrict__ xf,
                                                    const int* __restrict__ batch,
                                                    float* __restrict__ out) {
    __shared__ float red[8][DIM];
    int g = blockIdx.x;
    int j = threadIdx.x & 127;
    int rl = threadIdx.x >> 7;
    int lo = 0, hi = N_NODES;
    while (lo < hi) { int m = (lo + hi) >> 1; if (batch[m] < g) lo = m + 1; else hi = m; }
    int start = lo;
    lo = 0; hi = N_NODES;
    while (lo < hi) { int m = (lo + hi) >> 1; if (batch[m] < g + 1) lo = m + 1; else hi = m; }
    int end = lo;
    float acc = 0.f;
    for (int r = start + rl; r < end; r += 8) acc += xf[(size_t)r * DIM + j];
    red[rl][j] = acc;
    __syncthreads();
    if (rl == 0) {
        float s = ((red[0][j] + red[1][j]) + (red[2][j] + red[3][j]))
                + ((red[4][j] + red[5][j]) + (red[6][j] + red[7][j]));
        out[g * DIM + j] = s;
    }
}

// ---------------------------------------------------------------- launcher
extern "C" void kernel_launch(void* const* d_in, const int* in_sizes, int n_in,
                              void* d_out, int out_size, void* d_ws, size_t ws_size,
                              hipStream_t stream) {
    const float* x   = (const float*)d_in[0];
    const int*   ei  = (const int*)d_in[1];
    const int*   bat = (const int*)d_in[2];
    const float* Wl  = (const float*)d_in[3];
    const float* Wr  = (const float*)d_in[4];
    const float* b   = (const float*)d_in[5];
    float* out = (float*)d_out;

    char* ws = (char*)d_ws;
    size_t off = 0;
    auto carve = [&](size_t bytes) {
        void* p = ws + off;
        off += (bytes + 255) & ~(size_t)255;
        return p;
    };
    int*   deg     = (int*)carve(sizeof(int) * N_NODES);
    int*   fill    = (int*)carve(sizeof(int) * N_NODES);
    int*   row_ptr = (int*)carve(sizeof(int) * (N_NODES + 1));
    int*   bsums   = (int*)carve(sizeof(int) * 256);
    int*   csr     = (int*)carve(sizeof(int) * N_EDGES);
    float* inv_deg = (float*)carve(sizeof(float) * N_NODES);
    unsigned short* xb   = (unsigned short*)carve(2ull * N_NODES * DIM);
    unsigned short* actA = (unsigned short*)carve(2ull * N_NODES * DIM);
    unsigned short* actB = (unsigned short*)carve(2ull * N_NODES * DIM);
    unsigned short* aggb = (unsigned short*)carve(2ull * N_NODES * DIM);
    float* finalf = (float*)carve(sizeof(float) * (size_t)N_NODES * DIM);
    (void)ws_size; (void)in_sizes; (void)n_in; (void)out_size;

    const int nBlkN = (N_NODES + 255) / 256;
    const int n4    = N_NODES * DIM / 4;

    zero2_kernel<<<nBlkN, 256, 0, stream>>>(deg, fill, N_NODES);
    cvt_kernel<<<(n4 + 255) / 256, 256, 0, stream>>>((const float4*)x, (ushort4*)xb, n4);
    hist_slice_kernel<<<HCHUNK * NSLICE, 256, 0, stream>>>(ei, deg);
    scan_block_sums<<<nBlkN, 256, 0, stream>>>(deg, bsums, N_NODES);
    scan_offsets<<<1, 256, 0, stream>>>(bsums, nBlkN);
    scan_write<<<nBlkN, 256, 0, stream>>>(deg, bsums, row_ptr, inv_deg, N_NODES);
    fill_slice_kernel<<<FCHUNK * NSLICE, 256, 0, stream>>>(ei, row_ptr, fill, csr);

    const int aggGrid  = (N_NODES * 64 + 255) / 256;
    const int gemmGrid = (N_NODES + GR - 1) / GR;

    // layer 0
    agg_kernel<<<aggGrid, 256, 0, stream>>>((const ushort4*)xb, csr, row_ptr, inv_deg,
                                            (ushort4*)aggb, N_NODES);
    gemm_kernel<1, 1><<<gemmGrid, 256, 0, stream>>>(aggb, xb, Wl, Wr, b, actA, nullptr, N_NODES);
    // layer 1
    agg_kernel<<<aggGrid, 256, 0, stream>>>((const ushort4*)actA, csr, row_ptr, inv_deg,
                                            (ushort4*)aggb, N_NODES);
    gemm_kernel<1, 1><<<gemmGrid, 256, 0, stream>>>(aggb, actA, Wl + DIM * DIM, Wr + DIM * DIM,
                                                    b + DIM, actB, nullptr, N_NODES);
    // layer 2 (f32 out, no relu)
    agg_kernel<<<aggGrid, 256, 0, stream>>>((const ushort4*)actB, csr, row_ptr, inv_deg,
                                            (ushort4*)aggb, N_NODES);
    gemm_kernel<0, 0><<<gemmGrid, 256, 0, stream>>>(aggb, actB, Wl + 2 * DIM * DIM,
                                                    Wr + 2 * DIM * DIM, b + 2 * DIM,
                                                    nullptr, finalf, N_NODES);

    pool_kernel<<<N_GRAPHS, 1024, 0, stream>>>(finalf, bat, out);
}

// Round 5
// 479.390 us; speedup vs baseline: 1.4766x; 1.4766x over previous
//
#include <hip/hip_runtime.h>
#include <hip/hip_bf16.h>

#define N_NODES 50000
#define N_EDGES 1600000
#define DIM 128
#define N_LAYERS 3
#define N_GRAPHS 128

typedef __attribute__((ext_vector_type(8))) short bf16x8;
typedef __attribute__((ext_vector_type(4))) float f32x4;

// ------------------------------------------------------------ bf16 helpers
__device__ __forceinline__ float bfu2f(unsigned short u) {
    union { unsigned int i; float f; } c; c.i = ((unsigned int)u) << 16; return c.f;
}
__device__ __forceinline__ unsigned short f2bfu(float f) {
    __hip_bfloat16 h = __float2bfloat16(f);  // RNE
    return *reinterpret_cast<unsigned short*>(&h);
}

// ---------------------------------------------------------------- utilities
__global__ void zero2_kernel(int* __restrict__ a, int* __restrict__ b, int n) {
    int i = blockIdx.x * blockDim.x + threadIdx.x;
    if (i < n) { a[i] = 0; b[i] = 0; }
}

__global__ __launch_bounds__(256) void cvt_kernel(const float4* __restrict__ x,
                                                  ushort4* __restrict__ xb, int n4) {
    int i = blockIdx.x * blockDim.x + threadIdx.x;
    if (i < n4) {
        float4 v = x[i];
        ushort4 o;
        o.x = f2bfu(v.x); o.y = f2bfu(v.y); o.z = f2bfu(v.z); o.w = f2bfu(v.w);
        xb[i] = o;
    }
}

// Pack W into MFMA-fragment-major bf16:
// index t = (((layer*2+mat)*4+kt)*8+ct)*64+lane ; elem j=0..7
// value = W_mat[layer][k = kt*32 + (lane>>4)*8 + j][n = ct*16 + (lane&15)]
__global__ __launch_bounds__(256) void pack_w_kernel(const float* __restrict__ Wl,
                                                     const float* __restrict__ Wr,
                                                     unsigned short* __restrict__ wp) {
    int t = blockIdx.x * blockDim.x + threadIdx.x;
    if (t >= 3 * 2 * 4 * 8 * 64) return;
    int lane = t & 63;
    int rest = t >> 6;
    int ct = rest & 7; rest >>= 3;
    int kt = rest & 3; rest >>= 2;
    int mat = rest & 1; rest >>= 1;
    int layer = rest;
    const float* W = (mat ? Wr : Wl) + (size_t)layer * DIM * DIM;
    int col = ct * 16 + (lane & 15);
    int k0 = kt * 32 + (lane >> 4) * 8;
    unsigned short* dst = wp + (size_t)t * 8;
#pragma unroll
    for (int j = 0; j < 8; j++) dst[j] = f2bfu(W[(k0 + j) * DIM + col]);
}

// ------------------------------------------------------------- CSR building
__global__ void hist_kernel(const int* __restrict__ ei, int* __restrict__ deg, int ne) {
    int e = blockIdx.x * blockDim.x + threadIdx.x;
    if (e < ne) atomicAdd(&deg[ei[N_EDGES + e]], 1);
}

__global__ __launch_bounds__(256) void scan_block_sums(const int* __restrict__ deg,
                                                       int* __restrict__ bsums, int n) {
    __shared__ int sd[256];
    int tid = threadIdx.x;
    int i = blockIdx.x * 256 + tid;
    sd[tid] = (i < n) ? deg[i] : 0;
    __syncthreads();
    for (int off = 1; off < 256; off <<= 1) {
        int t = (tid >= off) ? sd[tid - off] : 0;
        __syncthreads();
        sd[tid] += t;
        __syncthreads();
    }
    if (tid == 255) bsums[blockIdx.x] = sd[255];
}

__global__ __launch_bounds__(256) void scan_offsets(int* __restrict__ bsums, int nb) {
    __shared__ int sd[256];
    int tid = threadIdx.x;
    int v = (tid < nb) ? bsums[tid] : 0;
    sd[tid] = v;
    __syncthreads();
    for (int off = 1; off < 256; off <<= 1) {
        int t = (tid >= off) ? sd[tid - off] : 0;
        __syncthreads();
        sd[tid] += t;
        __syncthreads();
    }
    if (tid < nb) bsums[tid] = sd[tid] - v;  // exclusive
}

__global__ __launch_bounds__(256) void scan_write(const int* __restrict__ deg,
                                                  const int* __restrict__ bsums,
                                                  int* __restrict__ row_ptr,
                                                  float* __restrict__ inv_deg, int n) {
    __shared__ int sd[256];
    int tid = threadIdx.x;
    int i = blockIdx.x * 256 + tid;
    int v = (i < n) ? deg[i] : 0;
    sd[tid] = v;
    __syncthreads();
    for (int off = 1; off < 256; off <<= 1) {
        int t = (tid >= off) ? sd[tid - off] : 0;
        __syncthreads();
        sd[tid] += t;
        __syncthreads();
    }
    if (i < n) {
        row_ptr[i + 1] = bsums[blockIdx.x] + sd[tid];
        inv_deg[i] = (v > 0) ? 1.0f / (float)v : 0.0f;
    }
    if (i == 0) row_ptr[0] = 0;
}

__global__ void fill_csr_kernel(const int* __restrict__ ei,
                                const int* __restrict__ row_ptr,
                                int* __restrict__ fill,
                                int* __restrict__ csr, int ne) {
    int e = blockIdx.x * blockDim.x + threadIdx.x;
    if (e < ne) {
        int s = ei[e];
        int d = ei[N_EDGES + e];
        int pos = atomicAdd(&fill[d], 1);
        csr[row_ptr[d] + pos] = s;
    }
}

// ------------------------------------------------------------- aggregation
// one wave per node; half-split pairs of edges, ushort4 (8B) per lane
__global__ __launch_bounds__(256) void agg_kernel(const ushort4* __restrict__ xb4,
                                                  const int* __restrict__ csr,
                                                  const int* __restrict__ row_ptr,
                                                  const float* __restrict__ inv_deg,
                                                  ushort4* __restrict__ aggb4, int n) {
    int gw = (blockIdx.x * blockDim.x + threadIdx.x) >> 6;
    int lane = threadIdx.x & 63;
    if (gw >= n) return;
    const int half = lane >> 5;
    const int sub  = lane & 31;
    int e0 = row_ptr[gw], e1 = row_ptr[gw + 1];
    float a0 = 0.f, a1 = 0.f, a2 = 0.f, a3 = 0.f;
    int e = e0;
    for (; e + 4 <= e1; e += 4) {
        int sA = csr[e + half];
        int sB = csr[e + 2 + half];
        ushort4 vA = xb4[(size_t)sA * 32 + sub];
        ushort4 vB = xb4[(size_t)sB * 32 + sub];
        a0 += bfu2f(vA.x) + bfu2f(vB.x);
        a1 += bfu2f(vA.y) + bfu2f(vB.y);
        a2 += bfu2f(vA.z) + bfu2f(vB.z);
        a3 += bfu2f(vA.w) + bfu2f(vB.w);
    }
    if (e + 2 <= e1) {
        int s = csr[e + half];
        ushort4 v = xb4[(size_t)s * 32 + sub];
        a0 += bfu2f(v.x); a1 += bfu2f(v.y); a2 += bfu2f(v.z); a3 += bfu2f(v.w);
        e += 2;
    }
    if (e < e1 && half == 0) {
        int s = csr[e];
        ushort4 v = xb4[(size_t)s * 32 + sub];
        a0 += bfu2f(v.x); a1 += bfu2f(v.y); a2 += bfu2f(v.z); a3 += bfu2f(v.w);
    }
    a0 += __shfl_xor(a0, 32);
    a1 += __shfl_xor(a1, 32);
    a2 += __shfl_xor(a2, 32);
    a3 += __shfl_xor(a3, 32);
    if (half == 0) {
        float w = inv_deg[gw];
        ushort4 o;
        o.x = f2bfu(a0 * w); o.y = f2bfu(a1 * w);
        o.z = f2bfu(a2 * w); o.w = f2bfu(a3 * w);
        aggb4[(size_t)gw * 32 + sub] = o;
    }
}

// ---------------------------------------------------------------- MFMA GEMM
// out = [agg | x] @ [Wl ; Wr] + bias (+ReLU).
// wave = 2 row-tiles x 4 col-tiles, K = 256 (128 agg + 128 x), no LDS.
// A-frag: lane l holds A[m=l&15][k=(l>>4)*8 + j], j=0..7 (16B contiguous load).
// B-frag: packed by pack_w_kernel. C/D: col=l&15, row=(l>>4)*4+reg (m89 layout).
template <int OUT_BF16, int RELU>
__global__ __launch_bounds__(256) void gemm_mfma_kernel(
    const unsigned short* __restrict__ aggb,
    const unsigned short* __restrict__ xb,
    const unsigned short* __restrict__ wp,   // this layer, both mats packed
    const float* __restrict__ bias,
    unsigned short* __restrict__ outb,
    float* __restrict__ outf) {
    const int NT = N_NODES / 16;  // 3125 row-tiles (exact)
    int wid = (blockIdx.x * blockDim.x + threadIdx.x) >> 6;
    int lane = threadIdx.x & 63;
    int ch  = wid & 1;       // column half (4 col-tiles each)
    int rt0 = (wid >> 1) * 2;
    if (rt0 >= NT) return;
    const bool has1 = (rt0 + 1) < NT;
    const int R0 = rt0 * 16, R1 = R0 + 16;
    const int l15 = lane & 15, l4 = lane >> 4;

    f32x4 acc[2][4];
#pragma unroll
    for (int c = 0; c < 4; c++) {
        float bv = bias[(ch * 4 + c) * 16 + l15];
        acc[0][c] = (f32x4){bv, bv, bv, bv};
        acc[1][c] = acc[0][c];
    }

#pragma unroll
    for (int mat = 0; mat < 2; mat++) {
        const unsigned short* src = mat ? xb : aggb;
        const unsigned short* wbase = wp + mat * (4 * 8 * 64 * 8);
#pragma unroll
        for (int kt = 0; kt < 4; kt++) {
            bf16x8 a0 = *(const bf16x8*)(src + (size_t)(R0 + l15) * DIM + kt * 32 + l4 * 8);
            bf16x8 a1 = {};
            if (has1) a1 = *(const bf16x8*)(src + (size_t)(R1 + l15) * DIM + kt * 32 + l4 * 8);
            const unsigned short* wk = wbase + kt * (8 * 64 * 8) + lane * 8;
#pragma unroll
            for (int c = 0; c < 4; c++) {
                bf16x8 bf = *(const bf16x8*)(wk + (ch * 4 + c) * (64 * 8));
                acc[0][c] = __builtin_amdgcn_mfma_f32_16x16x32_bf16(a0, bf, acc[0][c], 0, 0, 0);
                if (has1)
                    acc[1][c] = __builtin_amdgcn_mfma_f32_16x16x32_bf16(a1, bf, acc[1][c], 0, 0, 0);
            }
        }
    }

#pragma unroll
    for (int m = 0; m < 2; m++) {
        if (m && !has1) break;
        int r0 = (m ? R1 : R0) + l4 * 4;
#pragma unroll
        for (int c = 0; c < 4; c++) {
            int col = (ch * 4 + c) * 16 + l15;
#pragma unroll
            for (int j = 0; j < 4; j++) {
                float v = acc[m][c][j];
                if (RELU) v = fmaxf(v, 0.f);
                if (OUT_BF16) outb[(size_t)(r0 + j) * DIM + col] = f2bfu(v);
                else          outf[(size_t)(r0 + j) * DIM + col] = v;
            }
        }
    }
}

// ------------------------------------------------------------------- pool
__global__ __launch_bounds__(1024) void pool_kernel(const float* __restrict__ xf,
                                                    const int* __restrict__ batch,
                                                    float* __restrict__ out) {
    __shared__ float red[8][DIM];
    int g = blockIdx.x;
    int j = threadIdx.x & 127;
    int rl = threadIdx.x >> 7;
    int lo = 0, hi = N_NODES;
    while (lo < hi) { int m = (lo + hi) >> 1; if (batch[m] < g) lo = m + 1; else hi = m; }
    int start = lo;
    lo = 0; hi = N_NODES;
    while (lo < hi) { int m = (lo + hi) >> 1; if (batch[m] < g + 1) lo = m + 1; else hi = m; }
    int end = lo;
    float acc = 0.f;
    for (int r = start + rl; r < end; r += 8) acc += xf[(size_t)r * DIM + j];
    red[rl][j] = acc;
    __syncthreads();
    if (rl == 0) {
        float s = ((red[0][j] + red[1][j]) + (red[2][j] + red[3][j]))
                + ((red[4][j] + red[5][j]) + (red[6][j] + red[7][j]));
        out[g * DIM + j] = s;
    }
}

// ---------------------------------------------------------------- launcher
extern "C" void kernel_launch(void* const* d_in, const int* in_sizes, int n_in,
                              void* d_out, int out_size, void* d_ws, size_t ws_size,
                              hipStream_t stream) {
    const float* x   = (const float*)d_in[0];
    const int*   ei  = (const int*)d_in[1];
    const int*   bat = (const int*)d_in[2];
    const float* Wl  = (const float*)d_in[3];
    const float* Wr  = (const float*)d_in[4];
    const float* b   = (const float*)d_in[5];
    float* out = (float*)d_out;

    char* ws = (char*)d_ws;
    size_t off = 0;
    auto carve = [&](size_t bytes) {
        void* p = ws + off;
        off += (bytes + 255) & ~(size_t)255;
        return p;
    };
    int*   deg     = (int*)carve(sizeof(int) * N_NODES);
    int*   fill    = (int*)carve(sizeof(int) * N_NODES);
    int*   row_ptr = (int*)carve(sizeof(int) * (N_NODES + 1));
    int*   bsums   = (int*)carve(sizeof(int) * 256);
    int*   csr     = (int*)carve(sizeof(int) * N_EDGES);
    float* inv_deg = (float*)carve(sizeof(float) * N_NODES);
    unsigned short* xb    = (unsigned short*)carve(2ull * N_NODES * DIM);
    unsigned short* actA  = (unsigned short*)carve(2ull * N_NODES * DIM);
    unsigned short* actB  = (unsigned short*)carve(2ull * N_NODES * DIM);
    unsigned short* aggb  = (unsigned short*)carve(2ull * N_NODES * DIM);
    unsigned short* wpack = (unsigned short*)carve(2ull * 3 * 2 * 4 * 8 * 64 * 8);
    float* finalf = (float*)carve(sizeof(float) * (size_t)N_NODES * DIM);
    (void)ws_size; (void)in_sizes; (void)n_in; (void)out_size;

    const int nBlkN = (N_NODES + 255) / 256;
    const int nBlkE = (N_EDGES + 255) / 256;
    const int n4    = N_NODES * DIM / 4;

    zero2_kernel<<<nBlkN, 256, 0, stream>>>(deg, fill, N_NODES);
    cvt_kernel<<<(n4 + 255) / 256, 256, 0, stream>>>((const float4*)x, (ushort4*)xb, n4);
    pack_w_kernel<<<48, 256, 0, stream>>>(Wl, Wr, wpack);
    hist_kernel<<<nBlkE, 256, 0, stream>>>(ei, deg, N_EDGES);
    scan_block_sums<<<nBlkN, 256, 0, stream>>>(deg, bsums, N_NODES);
    scan_offsets<<<1, 256, 0, stream>>>(bsums, nBlkN);
    scan_write<<<nBlkN, 256, 0, stream>>>(deg, bsums, row_ptr, inv_deg, N_NODES);
    fill_csr_kernel<<<nBlkE, 256, 0, stream>>>(ei, row_ptr, fill, csr, N_EDGES);

    const int aggGrid  = (N_NODES * 64 + 255) / 256;
    // GEMM: 3126 waves -> 782 blocks of 256 threads
    const int gemmGrid = ((N_NODES / 16 + 1) / 2 * 2 * 64 + 255) / 256;
    const size_t wlayer = 2ull * 4 * 8 * 64 * 8;  // shorts per layer

    // layer 0
    agg_kernel<<<aggGrid, 256, 0, stream>>>((const ushort4*)xb, csr, row_ptr, inv_deg,
                                            (ushort4*)aggb, N_NODES);
    gemm_mfma_kernel<1, 1><<<gemmGrid, 256, 0, stream>>>(aggb, xb, wpack + 0 * wlayer,
                                                         b + 0 * DIM, actA, nullptr);
    // layer 1
    agg_kernel<<<aggGrid, 256, 0, stream>>>((const ushort4*)actA, csr, row_ptr, inv_deg,
                                            (ushort4*)aggb, N_NODES);
    gemm_mfma_kernel<1, 1><<<gemmGrid, 256, 0, stream>>>(aggb, actA, wpack + 1 * wlayer,
                                                         b + 1 * DIM, actB, nullptr);
    // layer 2 (f32 out, no relu)
    agg_kernel<<<aggGrid, 256, 0, stream>>>((const ushort4*)actB, csr, row_ptr, inv_deg,
                                            (ushort4*)aggb, N_NODES);
    gemm_mfma_kernel<0, 0><<<gemmGrid, 256, 0, stream>>>(aggb, actB, wpack + 2 * wlayer,
                                                         b + 2 * DIM, nullptr, finalf);

    pool_kernel<<<N_GRAPHS, 1024, 0, stream>>>(finalf, bat, out);
}

// Round 6
// 290.923 us; speedup vs baseline: 2.4332x; 1.6478x over previous
//
#include <hip/hip_runtime.h>
#include <hip/hip_bf16.h>

#define N_NODES 50000
#define N_EDGES 1600000
#define DIM 128
#define N_LAYERS 3
#define N_GRAPHS 128

#define NBUCK 196          // ceil(50000/256) buckets of 256 nodes
#define T1 4096            // edges per partition block
#define G1 ((N_EDGES + T1 - 1) / T1)   // 391

typedef __attribute__((ext_vector_type(8))) short bf16x8;
typedef __attribute__((ext_vector_type(4))) float f32x4;

// ------------------------------------------------------------ bf16 helpers
__device__ __forceinline__ float bfu2f(unsigned short u) {
    union { unsigned int i; float f; } c; c.i = ((unsigned int)u) << 16; return c.f;
}
__device__ __forceinline__ unsigned short f2bfu(float f) {
    __hip_bfloat16 h = __float2bfloat16(f);  // RNE
    return *reinterpret_cast<unsigned short*>(&h);
}

// ---------------------------------------------------------------- utilities
__global__ void zero_counts_kernel(int* __restrict__ bc) {
    if (threadIdx.x < 256) bc[threadIdx.x] = 0;
}

__global__ __launch_bounds__(256) void cvt_kernel(const float4* __restrict__ x,
                                                  ushort4* __restrict__ xb, int n4) {
    int i = blockIdx.x * blockDim.x + threadIdx.x;
    if (i < n4) {
        float4 v = x[i];
        ushort4 o;
        o.x = f2bfu(v.x); o.y = f2bfu(v.y); o.z = f2bfu(v.z); o.w = f2bfu(v.w);
        xb[i] = o;
    }
}

// Pack W into MFMA-fragment-major bf16 (layout verified in round 5):
// t = (((layer*2+mat)*4+kt)*8+ct)*64+lane ; elem j -> W[k=kt*32+(lane>>4)*8+j][n=ct*16+(lane&15)]
__global__ __launch_bounds__(256) void pack_w_kernel(const float* __restrict__ Wl,
                                                     const float* __restrict__ Wr,
                                                     unsigned short* __restrict__ wp) {
    int t = blockIdx.x * blockDim.x + threadIdx.x;
    if (t >= 3 * 2 * 4 * 8 * 64) return;
    int lane = t & 63;
    int rest = t >> 6;
    int ct = rest & 7; rest >>= 3;
    int kt = rest & 3; rest >>= 2;
    int mat = rest & 1; rest >>= 1;
    int layer = rest;
    const float* W = (mat ? Wr : Wl) + (size_t)layer * DIM * DIM;
    int col = ct * 16 + (lane & 15);
    int k0 = kt * 32 + (lane >> 4) * 8;
    unsigned short* dst = wp + (size_t)t * 8;
#pragma unroll
    for (int j = 0; j < 8; j++) dst[j] = f2bfu(W[(k0 + j) * DIM + col]);
}

// --------------------------------------------------- CSR build, bucket-sorted
// pass0: per-block LDS histogram of bucket (dst>>8) counts
__global__ __launch_bounds__(256) void pass0_bcount(const int* __restrict__ ei,
                                                    int* __restrict__ bcount) {
    __shared__ int h[256];
    int tid = threadIdx.x;
    h[tid] = 0;
    __syncthreads();
    int e0 = blockIdx.x * T1;
    int e1 = min(e0 + T1, N_EDGES);
    for (int e = e0 + tid; e < e1; e += 256) atomicAdd(&h[ei[N_EDGES + e] >> 8], 1);
    __syncthreads();
    if (h[tid]) atomicAdd(&bcount[tid], h[tid]);
}

// scan bucket counts -> bbase (exclusive, 197 entries) and cursor copy
__global__ __launch_bounds__(256) void scan196_kernel(const int* __restrict__ bcount,
                                                      int* __restrict__ bbase,
                                                      int* __restrict__ cursor) {
    __shared__ int sc[256];
    int tid = threadIdx.x;
    int v = (tid < NBUCK) ? bcount[tid] : 0;
    sc[tid] = v;
    __syncthreads();
    for (int off = 1; off < 256; off <<= 1) {
        int t = (tid >= off) ? sc[tid - off] : 0;
        __syncthreads();
        sc[tid] += t;
        __syncthreads();
    }
    int excl = sc[tid] - v;
    if (tid <= NBUCK) {  // bbase[0..195] from excl; bbase[196] via thread 195's incl
        bbase[tid] = excl;
        cursor[tid] = excl;
    }
    if (tid == NBUCK - 1) bbase[NBUCK] = sc[tid];
}

// pass1: LDS bucket-sort a 4096-edge tile, append per-bucket runs to pairs[]
__global__ __launch_bounds__(256) void pass1_partition(const int* __restrict__ ei,
                                                       int* __restrict__ cursor,
                                                       int2* __restrict__ pairs) {
    __shared__ int h[256], sc[256], o[256], c[256], gb[256];
    __shared__ int2 stg[T1];
    int tid = threadIdx.x;
    int e0 = blockIdx.x * T1;
    int e1 = min(e0 + T1, N_EDGES);
    h[tid] = 0;
    __syncthreads();
    for (int e = e0 + tid; e < e1; e += 256) atomicAdd(&h[ei[N_EDGES + e] >> 8], 1);
    __syncthreads();
    int myc = h[tid];
    sc[tid] = myc;
    __syncthreads();
    for (int off = 1; off < 256; off <<= 1) {
        int t = (tid >= off) ? sc[tid - off] : 0;
        __syncthreads();
        sc[tid] += t;
        __syncthreads();
    }
    o[tid] = sc[tid] - myc;
    c[tid] = o[tid];
    __syncthreads();
    for (int e = e0 + tid; e < e1; e += 256) {
        int s = ei[e];
        int d = ei[N_EDGES + e];
        int p = atomicAdd(&c[d >> 8], 1);
        stg[p] = make_int2(s, d);
    }
    __syncthreads();
    if (tid < NBUCK && myc) gb[tid] = atomicAdd(&cursor[tid], myc);
    __syncthreads();
    int cnt = e1 - e0;
    for (int j = tid; j < cnt; j += 256) {
        int2 pr = stg[j];
        int bk = pr.y >> 8;
        pairs[gb[bk] + (j - o[bk])] = pr;
    }
}

// pass2: one block per bucket; local deg/row_ptr/inv_deg + L2-resident scatter
__global__ __launch_bounds__(256) void pass2_fill(const int2* __restrict__ pairs,
                                                  const int* __restrict__ bbase,
                                                  int* __restrict__ row_ptr,
                                                  float* __restrict__ inv_deg,
                                                  int* __restrict__ csr) {
    __shared__ int lh[256], sc[256], lf[256];
    int tid = threadIdx.x;
    int b = blockIdx.x;
    int n0 = b << 8;
    int p0 = bbase[b], p1 = bbase[b + 1];
    lh[tid] = 0;
    __syncthreads();
    for (int p = p0 + tid; p < p1; p += 256) atomicAdd(&lh[pairs[p].y & 255], 1);
    __syncthreads();
    int deg = lh[tid];
    sc[tid] = deg;
    __syncthreads();
    for (int off = 1; off < 256; off <<= 1) {
        int t = (tid >= off) ? sc[tid - off] : 0;
        __syncthreads();
        sc[tid] += t;
        __syncthreads();
    }
    int base = p0 + sc[tid] - deg;  // absolute csr offset of this node
    int node = n0 + tid;
    if (node < N_NODES) {
        row_ptr[node] = base;
        inv_deg[node] = (deg > 0) ? 1.0f / (float)deg : 0.0f;
    }
    if (b == NBUCK - 1 && tid == 0) row_ptr[N_NODES] = p1;
    lf[tid] = base;
    __syncthreads();
    for (int p = p0 + tid; p < p1; p += 256) {
        int2 pr = pairs[p];
        int pos = atomicAdd(&lf[pr.y & 255], 1);
        csr[pos] = pr.x;
    }
}

// ------------------------------------------------------------- aggregation
// one wave per node; 4 groups of 16 lanes; lane loads int4 (8 bf16);
// 4 edges per step pair-> 8 rows in flight; shfl_xor(16,32) combine.
__device__ __forceinline__ void acc8(int4 v, float* a) {
    union { int i; float f; } t;
    t.i = v.x << 16;         a[0] += t.f;
    t.i = v.x & 0xffff0000;  a[1] += t.f;
    t.i = v.y << 16;         a[2] += t.f;
    t.i = v.y & 0xffff0000;  a[3] += t.f;
    t.i = v.z << 16;         a[4] += t.f;
    t.i = v.z & 0xffff0000;  a[5] += t.f;
    t.i = v.w << 16;         a[6] += t.f;
    t.i = v.w & 0xffff0000;  a[7] += t.f;
}

__global__ __launch_bounds__(256) void agg_kernel(const unsigned short* __restrict__ xb,
                                                  const int* __restrict__ csr,
                                                  const int* __restrict__ row_ptr,
                                                  const float* __restrict__ inv_deg,
                                                  unsigned short* __restrict__ aggb, int n) {
    int gw = (blockIdx.x * blockDim.x + threadIdx.x) >> 6;
    int lane = threadIdx.x & 63;
    if (gw >= n) return;
    const int grp = lane >> 4;   // 0..3
    const int sub = lane & 15;   // feature block
    int e0 = row_ptr[gw], e1 = row_ptr[gw + 1];
    float a[8] = {0.f, 0.f, 0.f, 0.f, 0.f, 0.f, 0.f, 0.f};
    int e = e0;
    for (; e + 8 <= e1; e += 8) {
        int ia = csr[e + grp];
        int ib = csr[e + 4 + grp];
        int4 va = *(const int4*)(xb + (size_t)ia * DIM + sub * 8);
        int4 vb = *(const int4*)(xb + (size_t)ib * DIM + sub * 8);
        acc8(va, a);
        acc8(vb, a);
    }
    if (e + 4 <= e1) {
        int ia = csr[e + grp];
        int4 va = *(const int4*)(xb + (size_t)ia * DIM + sub * 8);
        acc8(va, a);
        e += 4;
    }
    int rem = e1 - e;  // 0..3
    if (grp < rem) {
        int ia = csr[e + grp];
        int4 va = *(const int4*)(xb + (size_t)ia * DIM + sub * 8);
        acc8(va, a);
    }
#pragma unroll
    for (int k = 0; k < 8; k++) {
        a[k] += __shfl_xor(a[k], 16);
        a[k] += __shfl_xor(a[k], 32);
    }
    if (grp == 0) {
        float w = inv_deg[gw];
        int4 o;
        o.x = ((int)f2bfu(a[1] * w) << 16) | f2bfu(a[0] * w);
        o.y = ((int)f2bfu(a[3] * w) << 16) | f2bfu(a[2] * w);
        o.z = ((int)f2bfu(a[5] * w) << 16) | f2bfu(a[4] * w);
        o.w = ((int)f2bfu(a[7] * w) << 16) | f2bfu(a[6] * w);
        *(int4*)(aggb + (size_t)gw * DIM + sub * 8) = o;
    }
}

// ---------------------------------------------------------------- MFMA GEMM
// out = [agg | x] @ [Wl ; Wr] + bias (+ReLU). Layout as round 5 (verified).
template <int OUT_BF16, int RELU>
__global__ __launch_bounds__(256) void gemm_mfma_kernel(
    const unsigned short* __restrict__ aggb,
    const unsigned short* __restrict__ xb,
    const unsigned short* __restrict__ wp,
    const float* __restrict__ bias,
    unsigned short* __restrict__ outb,
    float* __restrict__ outf) {
    const int NT = N_NODES / 16;  // 3125
    int wid = (blockIdx.x * blockDim.x + threadIdx.x) >> 6;
    int lane = threadIdx.x & 63;
    int ch  = wid & 1;
    int rt0 = (wid >> 1) * 2;
    if (rt0 >= NT) return;
    const bool has1 = (rt0 + 1) < NT;
    const int R0 = rt0 * 16, R1 = R0 + 16;
    const int l15 = lane & 15, l4 = lane >> 4;

    f32x4 acc[2][4];
#pragma unroll
    for (int c = 0; c < 4; c++) {
        float bv = bias[(ch * 4 + c) * 16 + l15];
        acc[0][c] = (f32x4){bv, bv, bv, bv};
        acc[1][c] = acc[0][c];
    }

#pragma unroll
    for (int mat = 0; mat < 2; mat++) {
        const unsigned short* src = mat ? xb : aggb;
        const unsigned short* wbase = wp + mat * (4 * 8 * 64 * 8);
#pragma unroll
        for (int kt = 0; kt < 4; kt++) {
            bf16x8 a0 = *(const bf16x8*)(src + (size_t)(R0 + l15) * DIM + kt * 32 + l4 * 8);
            bf16x8 a1 = {};
            if (has1) a1 = *(const bf16x8*)(src + (size_t)(R1 + l15) * DIM + kt * 32 + l4 * 8);
            const unsigned short* wk = wbase + kt * (8 * 64 * 8) + lane * 8;
#pragma unroll
            for (int c = 0; c < 4; c++) {
                bf16x8 bf = *(const bf16x8*)(wk + (ch * 4 + c) * (64 * 8));
                acc[0][c] = __builtin_amdgcn_mfma_f32_16x16x32_bf16(a0, bf, acc[0][c], 0, 0, 0);
                if (has1)
                    acc[1][c] = __builtin_amdgcn_mfma_f32_16x16x32_bf16(a1, bf, acc[1][c], 0, 0, 0);
            }
        }
    }

#pragma unroll
    for (int m = 0; m < 2; m++) {
        if (m && !has1) break;
        int r0 = (m ? R1 : R0) + l4 * 4;
#pragma unroll
        for (int c = 0; c < 4; c++) {
            int col = (ch * 4 + c) * 16 + l15;
#pragma unroll
            for (int j = 0; j < 4; j++) {
                float v = acc[m][c][j];
                if (RELU) v = fmaxf(v, 0.f);
                if (OUT_BF16) outb[(size_t)(r0 + j) * DIM + col] = f2bfu(v);
                else          outf[(size_t)(r0 + j) * DIM + col] = v;
            }
        }
    }
}

// ------------------------------------------------------------------- pool
__global__ __launch_bounds__(1024) void pool_kernel(const float* __restrict__ xf,
                                                    const int* __restrict__ batch,
                                                    float* __restrict__ out) {
    __shared__ float red[8][DIM];
    int g = blockIdx.x;
    int j = threadIdx.x & 127;
    int rl = threadIdx.x >> 7;
    int lo = 0, hi = N_NODES;
    while (lo < hi) { int m = (lo + hi) >> 1; if (batch[m] < g) lo = m + 1; else hi = m; }
    int start = lo;
    lo = 0; hi = N_NODES;
    while (lo < hi) { int m = (lo + hi) >> 1; if (batch[m] < g + 1) lo = m + 1; else hi = m; }
    int end = lo;
    float acc = 0.f;
    for (int r = start + rl; r < end; r += 8) acc += xf[(size_t)r * DIM + j];
    red[rl][j] = acc;
    __syncthreads();
    if (rl == 0) {
        float s = ((red[0][j] + red[1][j]) + (red[2][j] + red[3][j]))
                + ((red[4][j] + red[5][j]) + (red[6][j] + red[7][j]));
        out[g * DIM + j] = s;
    }
}

// ---------------------------------------------------------------- launcher
extern "C" void kernel_launch(void* const* d_in, const int* in_sizes, int n_in,
                              void* d_out, int out_size, void* d_ws, size_t ws_size,
                              hipStream_t stream) {
    const float* x   = (const float*)d_in[0];
    const int*   ei  = (const int*)d_in[1];
    const int*   bat = (const int*)d_in[2];
    const float* Wl  = (const float*)d_in[3];
    const float* Wr  = (const float*)d_in[4];
    const float* b   = (const float*)d_in[5];
    float* out = (float*)d_out;

    char* ws = (char*)d_ws;
    size_t off = 0;
    auto carve = [&](size_t bytes) {
        void* p = ws + off;
        off += (bytes + 255) & ~(size_t)255;
        return p;
    };
    int*   bcount  = (int*)carve(sizeof(int) * 256);
    int*   bbase   = (int*)carve(sizeof(int) * 256);
    int*   cursor  = (int*)carve(sizeof(int) * 256);
    int*   row_ptr = (int*)carve(sizeof(int) * (N_NODES + 1));
    int*   csr     = (int*)carve(sizeof(int) * N_EDGES);
    float* inv_deg = (float*)carve(sizeof(float) * N_NODES);
    unsigned short* xb    = (unsigned short*)carve(2ull * N_NODES * DIM);
    unsigned short* actA  = (unsigned short*)carve(2ull * N_NODES * DIM);
    unsigned short* actB  = (unsigned short*)carve(2ull * N_NODES * DIM);
    unsigned short* aggb  = (unsigned short*)carve(2ull * N_NODES * DIM);
    unsigned short* wpack = (unsigned short*)carve(2ull * 3 * 2 * 4 * 8 * 64 * 8);
    float* finalf = (float*)carve(sizeof(float) * (size_t)N_NODES * DIM);
    // pairs aliases actB: dead before layer-1 gemm fully rewrites actB
    int2* pairs = (int2*)actB;   // N_EDGES * 8B == 2 * N_NODES * DIM bytes exactly
    (void)ws_size; (void)in_sizes; (void)n_in; (void)out_size;

    const int n4 = N_NODES * DIM / 4;

    zero_counts_kernel<<<1, 256, 0, stream>>>(bcount);
    cvt_kernel<<<(n4 + 255) / 256, 256, 0, stream>>>((const float4*)x, (ushort4*)xb, n4);
    pack_w_kernel<<<48, 256, 0, stream>>>(Wl, Wr, wpack);
    pass0_bcount<<<G1, 256, 0, stream>>>(ei, bcount);
    scan196_kernel<<<1, 256, 0, stream>>>(bcount, bbase, cursor);
    pass1_partition<<<G1, 256, 0, stream>>>(ei, cursor, pairs);
    pass2_fill<<<NBUCK, 256, 0, stream>>>(pairs, bbase, row_ptr, inv_deg, csr);

    const int aggGrid  = (N_NODES * 64 + 255) / 256;
    const int gemmGrid = ((N_NODES / 16 + 1) / 2 * 2 * 64 + 255) / 256;
    const size_t wlayer = 2ull * 4 * 8 * 64 * 8;

    // layer 0
    agg_kernel<<<aggGrid, 256, 0, stream>>>(xb, csr, row_ptr, inv_deg, aggb, N_NODES);
    gemm_mfma_kernel<1, 1><<<gemmGrid, 256, 0, stream>>>(aggb, xb, wpack + 0 * wlayer,
                                                         b + 0 * DIM, actA, nullptr);
    // layer 1
    agg_kernel<<<aggGrid, 256, 0, stream>>>(actA, csr, row_ptr, inv_deg, aggb, N_NODES);
    gemm_mfma_kernel<1, 1><<<gemmGrid, 256, 0, stream>>>(aggb, actA, wpack + 1 * wlayer,
                                                         b + 1 * DIM, actB, nullptr);
    // layer 2 (f32 out, no relu)
    agg_kernel<<<aggGrid, 256, 0, stream>>>(actB, csr, row_ptr, inv_deg, aggb, N_NODES);
    gemm_mfma_kernel<0, 0><<<gemmGrid, 256, 0, stream>>>(aggb, actB, wpack + 2 * wlayer,
                                                         b + 2 * DIM, nullptr, finalf);

    pool_kernel<<<N_GRAPHS, 1024, 0, stream>>>(finalf, bat, out);
}